// Round 19
// baseline (304.688 us; speedup 1.0000x reference)
//
#include <hip/hip_runtime.h>
#include <hip/hip_bf16.h>

// TransformerBlockQuantum on MI355X — bf16 MFMA pipeline, fp32 accumulate.
// B=4 S=2048 E=1024 F=4096 Q=8.
// R19: attn split-Q — QBLK 256->128, grid 512->1024 (4 blk/CU, ~16 waves/CU).
//     Per wave 32 q-rows (one group; qb1/p1 dropped, VGPR ~124->~90) to fix
//     the 17%-occupancy latency starvation. Everything else = R18.

typedef __attribute__((ext_vector_type(8))) short bf16x8;
typedef __attribute__((ext_vector_type(16))) float f32x16;
typedef __attribute__((ext_vector_type(4))) unsigned short u16x4;

__device__ __forceinline__ unsigned short f2bf(float f) {
  union { float f; unsigned int u; } v; v.f = f;
  return (unsigned short)((v.u + 0x7FFFu + ((v.u >> 16) & 1u)) >> 16);
}
__device__ __forceinline__ float bf2f(unsigned short h) {
  union { unsigned int u; float f; } v; v.u = ((unsigned int)h) << 16;
  return v.f;
}
__device__ __forceinline__ f32x16 mfma32(bf16x8 a, bf16x8 b, f32x16 c) {
  return __builtin_amdgcn_mfma_f32_32x32x16_bf16(a, b, c, 0, 0, 0);
}
// async global->LDS, 16B per lane. LDS dest = wave-uniform base (HW adds lane*16).
__device__ __forceinline__ void lds_cp16(const void* g, void* l) {
  __builtin_amdgcn_global_load_lds(
      (const __attribute__((address_space(1))) unsigned int*)g,
      (__attribute__((address_space(3))) unsigned int*)l, 16, 0, 0);
}

// C32-layout f32x16 (rows = r-dim over regs, cols = lane) -> two bf16 A32-frags
// (lane = col, elems = r-chunk h32*8+j and 16+h32*8+j). Pure VALU.
#define QG_CONV(P, FC0, FC1)                                                  \
  {                                                                           \
    int x0a, x0b, x1a, x1b, x2a, x2b, x3a, x3b;                               \
    asm("v_cvt_pk_bf16_f32 %0, %1, %2" : "=v"(x0a) : "v"(P[0]),  "v"(P[1]));  \
    asm("v_cvt_pk_bf16_f32 %0, %1, %2" : "=v"(x0b) : "v"(P[2]),  "v"(P[3]));  \
    asm("v_cvt_pk_bf16_f32 %0, %1, %2" : "=v"(x1a) : "v"(P[4]),  "v"(P[5]));  \
    asm("v_cvt_pk_bf16_f32 %0, %1, %2" : "=v"(x1b) : "v"(P[6]),  "v"(P[7]));  \
    asm("v_cvt_pk_bf16_f32 %0, %1, %2" : "=v"(x2a) : "v"(P[8]),  "v"(P[9]));  \
    asm("v_cvt_pk_bf16_f32 %0, %1, %2" : "=v"(x2b) : "v"(P[10]), "v"(P[11])); \
    asm("v_cvt_pk_bf16_f32 %0, %1, %2" : "=v"(x3a) : "v"(P[12]), "v"(P[13])); \
    asm("v_cvt_pk_bf16_f32 %0, %1, %2" : "=v"(x3b) : "v"(P[14]), "v"(P[15])); \
    asm("v_permlane32_swap_b32 %0, %1" : "+v"(x0a), "+v"(x1a));               \
    asm("v_permlane32_swap_b32 %0, %1" : "+v"(x0b), "+v"(x1b));               \
    asm("v_permlane32_swap_b32 %0, %1" : "+v"(x2a), "+v"(x3a));               \
    asm("v_permlane32_swap_b32 %0, %1" : "+v"(x2b), "+v"(x3b));               \
    union { int u[4]; bf16x8 v; } f0_, f1_;                                   \
    f0_.u[0] = x0a; f0_.u[1] = x0b; f0_.u[2] = x1a; f0_.u[3] = x1b;           \
    f1_.u[0] = x2a; f1_.u[1] = x2b; f1_.u[2] = x3a; f1_.u[3] = x3b;           \
    FC0 = f0_.v; FC1 = f1_.v;                                                 \
  }

// ---------------- cast x (f32 -> bf16), 4 elems/thread ----------------
__global__ __launch_bounds__(256) void cast_x_kernel(const float* __restrict__ in,
                                                     unsigned short* __restrict__ out,
                                                     int n4) {
  int i = blockIdx.x * 256 + threadIdx.x;
  if (i >= n4) return;
  float4 v = ((const float4*)in)[i];
  u16x4 o = { f2bf(v.x), f2bf(v.y), f2bf(v.z), f2bf(v.w) };
  ((u16x4*)out)[i] = o;
}

// ------------- fused weight prep: all transposes + w1t in ONE launch -------------
__global__ __launch_bounds__(256) void prep_weights(const float* __restrict__ wq,
                                                    const float* __restrict__ wk,
                                                    const float* __restrict__ wv,
                                                    const float* __restrict__ wo,
                                                    const float* __restrict__ w2,
                                                    const float* __restrict__ w1,
                                                    unsigned short* __restrict__ wqkvT,
                                                    unsigned short* __restrict__ woT,
                                                    unsigned short* __restrict__ w2T,
                                                    unsigned short* __restrict__ w1t) {
  __shared__ float tile[32][33];
  const int tx = threadIdx.x, ty = threadIdx.y;
  const int z = blockIdx.z;

  if (z == 0 && blockIdx.y >= 32) {
    if (blockIdx.y < 48) {
      const int f = (blockIdx.y - 32) * 256 + ty * 32 + tx;  // 0..4095
      unsigned short v[8];
#pragma unroll
      for (int q = 0; q < 8; q++) v[q] = f2bf(w1[q * 4096 + f]);
      *(u16x4*)(w1t + f * 8)     = (u16x4){v[0], v[1], v[2], v[3]};
      *(u16x4*)(w1t + f * 8 + 4) = (u16x4){v[4], v[5], v[6], v[7]};
    }
    return;
  }
  if (z < 4 && blockIdx.y >= 32) return;

  const float* src;
  unsigned short* dst;
  int K;
  if (z == 4)      { src = w2; dst = w2T; K = 4096; }
  else if (z == 0) { src = wq; dst = wqkvT; K = 1024; }
  else if (z == 1) { src = wk; dst = wqkvT + 1024 * 1024; K = 1024; }
  else if (z == 2) { src = wv; dst = wqkvT + 2048 * 1024; K = 1024; }
  else             { src = wo; dst = woT; K = 1024; }
  const int N = 1024;
  const int n0 = blockIdx.x * 32, k0 = blockIdx.y * 32;
#pragma unroll
  for (int i = 0; i < 32; i += 8)
    tile[ty + i][tx] = src[(long)(k0 + ty + i) * N + n0 + tx];
  __syncthreads();
#pragma unroll
  for (int i = 0; i < 32; i += 8)
    dst[(long)(n0 + ty + i) * K + k0 + tx] = f2bf(tile[tx][ty + i]);
}

// ------------- vT[bh][d=64][t=2048] = V[b,t,h,d] from qkv -------------
__global__ __launch_bounds__(256) void vt_kernel(const unsigned short* __restrict__ qkv,
                                                 unsigned short* __restrict__ vT) {
  __shared__ unsigned short tile[32][34];
  const int t0 = blockIdx.x * 32, d0 = blockIdx.y * 32, bh = blockIdx.z;
  const int b = bh >> 4, h = bh & 15;
  const int tx = threadIdx.x, ty = threadIdx.y;  // block (32,8)
  const unsigned short* src = qkv + (long)(b * 2048 + t0) * 3072 + 2048 + h * 64 + d0;
#pragma unroll
  for (int i = 0; i < 32; i += 8)
    tile[ty + i][tx] = src[(long)(ty + i) * 3072 + tx];
  __syncthreads();
  unsigned short* dst = vT + ((long)bh * 64 + d0) * 2048 + t0;
#pragma unroll
  for (int i = 0; i < 32; i += 8)
    dst[(long)(ty + i) * 2048 + tx] = tile[tx][ty + i];
}

// ---------------- GEMM: C[M,N] = A[M,K](bf16) @ BT[N,K](bf16)^T ----------------
// 128x128 tile, BK=64, 256 threads (4 waves 2Mx2N; per-wave 64x64, mfma32).
// 2 LDS buffers (64KB), counted vmcnt(8), XOR-swizzled LDS. (unchanged)
template<int EPI>  // 0: f32 out, 1: bf16 out
__global__ __launch_bounds__(256) void gemm_bt3(const unsigned short* __restrict__ A,
                                                const unsigned short* __restrict__ BT,
                                                void* __restrict__ Cv,
                                                int M, int N, int K) {
  __shared__ __align__(16) unsigned char smem[2][32768];  // per buf: A 16KB | B 16KB
  const int tid = threadIdx.x;
  const int l = tid & 63, w = tid >> 6;
  const int l32 = l & 31, h32 = l >> 5;
  const int wrm = (w >> 1) * 64;
  const int wrn = (w & 1) * 64;

  const int nx = gridDim.x;
  const int nwg = nx * gridDim.y;
  const int orig = blockIdx.y * nx + blockIdx.x;
  const int chunk = nwg >> 3;
  const int logical = (orig & 7) * chunk + (orig >> 3);
  const long m0 = (long)(logical / nx) * 128;
  const long n0 = (long)(logical % nx) * 128;

  const unsigned short* gp[8];
  unsigned ldsoff[8];
#pragma unroll
  for (int i = 0; i < 8; i++) {
    const int c = (i & 3) * 256 + tid;
    const int r = c >> 3, k8 = c & 7;
    if (i < 4) {
      gp[i] = A + (m0 + r) * (long)K + (k8 ^ (r & 7)) * 8;
      ldsoff[i] = (unsigned)c * 16;
    } else {
      gp[i] = BT + (n0 + r) * (long)K + (k8 ^ (r & 7)) * 8;
      ldsoff[i] = 16384u + (unsigned)c * 16;
    }
  }

  f32x16 acc[2][2];
#pragma unroll
  for (int mf = 0; mf < 2; mf++)
#pragma unroll
    for (int nf = 0; nf < 2; nf++)
#pragma unroll
      for (int e = 0; e < 16; e++) acc[mf][nf][e] = 0.f;

  const int NT = K >> 6;
#define STAGE(bf, t)                                                    \
  do {                                                                  \
    unsigned char* _d = &smem[bf][0];                                   \
    const long _ko = (long)(t) * 64;                                    \
    _Pragma("unroll")                                                   \
    for (int _i = 0; _i < 8; _i++)                                      \
      lds_cp16(gp[_i] + _ko, _d + ldsoff[_i]);                          \
  } while (0)

  STAGE(0, 0);
  int cur = 0;
  for (int t = 0; t < NT; t++) {
    if (t + 1 < NT) {
      STAGE(cur ^ 1, t + 1);
      asm volatile("s_waitcnt vmcnt(8)" ::: "memory");
    } else {
      asm volatile("s_waitcnt vmcnt(0)" ::: "memory");
    }
    __builtin_amdgcn_sched_barrier(0);
    __builtin_amdgcn_s_barrier();
    __builtin_amdgcn_sched_barrier(0);

    const unsigned char* bufA = &smem[cur][0];
    const unsigned char* bufB = &smem[cur][16384];
    bf16x8 af[2][4], bfr[2][4];
#pragma unroll
    for (int mf = 0; mf < 2; mf++) {
      const int r = wrm + mf * 32 + l32;
#pragma unroll
      for (int ks = 0; ks < 4; ks++)
        af[mf][ks] = *(const bf16x8*)(bufA + r * 128 + (((ks * 2 + h32) ^ (r & 7)) * 16));
    }
#pragma unroll
    for (int nf = 0; nf < 2; nf++) {
      const int r = wrn + nf * 32 + l32;
#pragma unroll
      for (int ks = 0; ks < 4; ks++)
        bfr[nf][ks] = *(const bf16x8*)(bufB + r * 128 + (((ks * 2 + h32) ^ (r & 7)) * 16));
    }
    __builtin_amdgcn_s_setprio(1);
#pragma unroll
    for (int ks = 0; ks < 4; ks++)
#pragma unroll
      for (int mf = 0; mf < 2; mf++)
#pragma unroll
        for (int nf = 0; nf < 2; nf++)
          acc[mf][nf] = mfma32(af[mf][ks], bfr[nf][ks], acc[mf][nf]);
    __builtin_amdgcn_s_setprio(0);
    __builtin_amdgcn_sched_barrier(0);
    __builtin_amdgcn_s_barrier();
    cur ^= 1;
  }
#undef STAGE

#pragma unroll
  for (int mf = 0; mf < 2; mf++)
#pragma unroll
    for (int nf = 0; nf < 2; nf++) {
      const long c0 = n0 + wrn + nf * 32 + l32;
#pragma unroll
      for (int reg = 0; reg < 16; reg++) {
        const long r0 = m0 + wrm + mf * 32 + (reg & 3) + 8 * (reg >> 2) + 4 * h32;
        if (EPI == 0) ((float*)Cv)[r0 * (long)N + c0] = acc[mf][nf][reg];
        else ((unsigned short*)Cv)[r0 * (long)N + c0] = f2bf(acc[mf][nf][reg]);
      }
    }
}

// ---------------- fused FFN, split-K, BN=256 (h converted once, used 2x) ----------
// (unchanged from R18)
__global__ __launch_bounds__(512) void ffn_fused(const unsigned short* __restrict__ qo,
                                                 const unsigned short* __restrict__ w1t,
                                                 const unsigned short* __restrict__ BT,
                                                 unsigned short* __restrict__ Cp0,
                                                 unsigned short* __restrict__ Cp1,
                                                 int N, int K) {
  __shared__ __align__(16) unsigned char sm[4 * 16384 + 32768 + 4096];
  unsigned char* lsW = sm + 65536;   // 32 slots x 1KB
  unsigned char* lsQ = sm + 98304;   // 256 rows x 16B
  const int tid = threadIdx.x;
  const int l = tid & 63, w = tid >> 6;
  const int l32 = l & 31, h32 = l >> 5;
  const int wrm = (w >> 1) * 64;   // 0,64,128,192
  const int wrn = (w & 1) * 64;    // 0,64

  const int nx = gridDim.x;                       // 4
  const int nwg = nx * gridDim.y;                 // 128 per kz
  const int orig = blockIdx.y * nx + blockIdx.x;
  const int chunk = nwg >> 3;
  const int logical = (orig & 7) * chunk + (orig >> 3);
  const long m0 = (long)(logical / nx) * 256;
  const long n0 = (long)(logical % nx) * 256;
  const int kz = blockIdx.z;
  const int NT = (K >> 6) >> 1;                   // 32 tiles per half
  const int tbase = kz * NT;
  unsigned short* C = kz ? Cp1 : Cp0;

  const unsigned short* gpB[2][2];
  unsigned offB[2];
#pragma unroll
  for (int i = 0; i < 2; i++) {
    const int c = i * 512 + tid;          // 0..1023: 128 rows x 8 chunks
    const int r = c >> 3, k8 = c & 7;
#pragma unroll
    for (int nt2 = 0; nt2 < 2; nt2++)
      gpB[nt2][i] = BT + (n0 + nt2 * 128 + r) * (long)K + (long)tbase * 64 + (k8 ^ (r & 7)) * 8;
    offB[i] = (unsigned)c * 16;
  }
  const unsigned short* w1base = w1t + (long)tbase * 64 * 8;

  const bf16x8 z8 = {0, 0, 0, 0, 0, 0, 0, 0};

#define STAGE_B(bf, t)                                                  \
  do {                                                                  \
    const long _ko = (long)(t) * 64;                                    \
    _Pragma("unroll")                                                   \
    for (int _n = 0; _n < 2; _n++) {                                    \
      unsigned char* _d = sm + ((bf) * 2 + _n) * 16384;                 \
      lds_cp16(gpB[_n][0] + _ko, _d + offB[0]);                         \
      lds_cp16(gpB[_n][1] + _ko, _d + offB[1]);                         \
    }                                                                   \
  } while (0)

  // prologue: ALL w1 slots (one wave each), qo strip, B tile 0 (both subtiles)
#pragma unroll
  for (int i = 0; i < 4; i++) {
    const int slot = i * 8 + w;
    lds_cp16(w1base + (long)(slot * 64 + l) * 8, lsW + ((unsigned)slot << 10));
  }
  if (w < 4) lds_cp16(qo + (m0 + w * 64 + l) * 8, lsQ + (unsigned)(w * 64) * 16);
  STAGE_B(0, 0);
  asm volatile("s_waitcnt vmcnt(0)" ::: "memory");
  __builtin_amdgcn_s_barrier();

  bf16x8 qof[2];
#pragma unroll
  for (int mf = 0; mf < 2; mf++)
    qof[mf] = (h32 == 0) ? *(const bf16x8*)(lsQ + (wrm + mf * 32 + l32) * 16) : z8;

  f32x16 zz;
#pragma unroll
  for (int e = 0; e < 16; e++) zz[e] = 0.f;
  f32x16 acc[2][2][2];   // [ntile][mf][nf]
#pragma unroll
  for (int nt2 = 0; nt2 < 2; nt2++)
#pragma unroll
    for (int mf = 0; mf < 2; mf++)
#pragma unroll
      for (int nf = 0; nf < 2; nf++) acc[nt2][mf][nf] = zz;

  int cur = 0;
  for (int t = 0; t < NT; t++) {
    if (t + 1 < NT) {
      STAGE_B(cur ^ 1, t + 1);
      asm volatile("s_waitcnt vmcnt(4)" ::: "memory");  // tile-t B resident
    } else {
      asm volatile("s_waitcnt vmcnt(0)" ::: "memory");
    }
    __builtin_amdgcn_sched_barrier(0);
    __builtin_amdgcn_s_barrier();
    __builtin_amdgcn_sched_barrier(0);

    // w1 frags (slot t); gen + relu + cvt BOTH mf h-tiles ONCE
    bf16x8 w1f[2];
#pragma unroll
    for (int tg = 0; tg < 2; tg++)
      w1f[tg] = (h32 == 0)
          ? *(const bf16x8*)(lsW + ((unsigned)t << 10) + (tg * 32 + l32) * 16) : z8;

    __builtin_amdgcn_s_setprio(1);
    f32x16 hC0 = mfma32(w1f[0], qof[0], zz);
    f32x16 hC1 = mfma32(w1f[1], qof[0], zz);
    f32x16 hD0 = mfma32(w1f[0], qof[1], zz);
    f32x16 hD1 = mfma32(w1f[1], qof[1], zz);
    __builtin_amdgcn_s_setprio(0);
#pragma unroll
    for (int e = 0; e < 16; e++) {
      hC0[e] = fmaxf(hC0[e], 0.f);
      hC1[e] = fmaxf(hC1[e], 0.f);
      hD0[e] = fmaxf(hD0[e], 0.f);
      hD1[e] = fmaxf(hD1[e], 0.f);
    }
    bf16x8 a0, a1, a2, a3, b0, b1, b2, b3;
    QG_CONV(hC0, a0, a1)
    QG_CONV(hC1, a2, a3)
    QG_CONV(hD0, b0, b1)
    QG_CONV(hD1, b2, b3)

    // apply to both N-subtiles
#pragma unroll
    for (int nt2 = 0; nt2 < 2; nt2++) {
      const unsigned char* bufB = sm + (cur * 2 + nt2) * 16384;
      bf16x8 bfr[2][4];
#pragma unroll
      for (int nf = 0; nf < 2; nf++) {
        const int r = wrn + nf * 32 + l32;
#pragma unroll
        for (int ks = 0; ks < 4; ks++)
          bfr[nf][ks] = *(const bf16x8*)(bufB + r * 128 + (((ks * 2 + h32) ^ (r & 7)) * 16));
      }
      __builtin_amdgcn_s_setprio(1);
      acc[nt2][0][0] = mfma32(a0, bfr[0][0], acc[nt2][0][0]);
      acc[nt2][0][0] = mfma32(a1, bfr[0][1], acc[nt2][0][0]);
      acc[nt2][0][0] = mfma32(a2, bfr[0][2], acc[nt2][0][0]);
      acc[nt2][0][0] = mfma32(a3, bfr[0][3], acc[nt2][0][0]);
      acc[nt2][0][1] = mfma32(a0, bfr[1][0], acc[nt2][0][1]);
      acc[nt2][0][1] = mfma32(a1, bfr[1][1], acc[nt2][0][1]);
      acc[nt2][0][1] = mfma32(a2, bfr[1][2], acc[nt2][0][1]);
      acc[nt2][0][1] = mfma32(a3, bfr[1][3], acc[nt2][0][1]);
      acc[nt2][1][0] = mfma32(b0, bfr[0][0], acc[nt2][1][0]);
      acc[nt2][1][0] = mfma32(b1, bfr[0][1], acc[nt2][1][0]);
      acc[nt2][1][0] = mfma32(b2, bfr[0][2], acc[nt2][1][0]);
      acc[nt2][1][0] = mfma32(b3, bfr[0][3], acc[nt2][1][0]);
      acc[nt2][1][1] = mfma32(b0, bfr[1][0], acc[nt2][1][1]);
      acc[nt2][1][1] = mfma32(b1, bfr[1][1], acc[nt2][1][1]);
      acc[nt2][1][1] = mfma32(b2, bfr[1][2], acc[nt2][1][1]);
      acc[nt2][1][1] = mfma32(b3, bfr[1][3], acc[nt2][1][1]);
      __builtin_amdgcn_s_setprio(0);
    }

    __builtin_amdgcn_sched_barrier(0);
    __builtin_amdgcn_s_barrier();
    cur ^= 1;
  }
#undef STAGE_B

#pragma unroll
  for (int nt2 = 0; nt2 < 2; nt2++)
#pragma unroll
    for (int mf = 0; mf < 2; mf++)
#pragma unroll
      for (int nf = 0; nf < 2; nf++) {
        const long c0 = n0 + nt2 * 128 + wrn + nf * 32 + l32;
#pragma unroll
        for (int reg = 0; reg < 16; reg++) {
          const long r0 = m0 + wrm + mf * 32 + (reg & 3) + 8 * (reg >> 2) + 4 * h32;
          C[r0 * (long)N + c0] = f2bf(acc[nt2][mf][nf][reg]);
        }
      }
}

// ---------------- flash attention: 32x32x16, swapped QK^T, split-Q ----------------
// R19: 128 q-rows/block (wave owns 32), grid 1024 -> 4 blk/CU.
#define QG_BLOCK(P, LIP, FC0, FC1)                                            \
  {                                                                           \
    _Pragma("unroll")                                                         \
    for (int e = 0; e < 16; e++)                                              \
      asm("v_exp_f32 %0, %1" : "=v"(P[e]) : "v"(P[e]));                       \
    float s_ = 0.f;                                                           \
    _Pragma("unroll")                                                         \
    for (int e = 0; e < 16; e++) s_ += P[e];                                  \
    LIP += s_;                                                                \
    QG_CONV(P, FC0, FC1)                                                      \
  }

__global__ __launch_bounds__(256) void attn_kernel(const unsigned short* __restrict__ qkv,
                                                   const unsigned short* __restrict__ vT,
                                                   unsigned short* __restrict__ ctx) {
  __shared__ __align__(16) unsigned short lsK[64][72];      // [t][d]
  __shared__ __align__(16) unsigned short lsV[64][72];      // [d][t]

  const int tid = threadIdx.x;
  const int l = tid & 63, w = tid >> 6;
  const int l32 = l & 31, h32 = l >> 5;

  const int orig = blockIdx.x;                  // 0..1023
  const int logical = (orig & 7) * 128 + (orig >> 3);
  const int s0 = (logical & 15) * 128;
  const int bh = logical >> 4;
  const int b = bh >> 4, hh = bh & 15;

  const float QSC = 0.18033688f;
  // Q B-frags: q = s0 + w*32 + l32, d = kc*16 + h32*8 .. +7 (one 32-row group)
  const unsigned short* qg_base = qkv + (long)(b * 2048 + s0 + w * 32) * 3072 + hh * 64;
  bf16x8 qb0[4];
#pragma unroll
  for (int kc = 0; kc < 4; kc++) {
    bf16x8 t0v = *(const bf16x8*)(qg_base + (long)l32 * 3072 + kc * 16 + h32 * 8);
#pragma unroll
    for (int j = 0; j < 8; j++)
      t0v[j] = (short)f2bf(bf2f((unsigned short)t0v[j]) * QSC);
    qb0[kc] = t0v;
  }

  f32x16 oacc00, oacc01;
#pragma unroll
  for (int e = 0; e < 16; e++) { oacc00[e] = 0.f; oacc01[e] = 0.f; }
  float lip0 = 0.f;

  const int tr = tid >> 2;            // 0..63
  const int tc = (tid & 3) * 16;
  const unsigned short* kbase = qkv + (long)(b * 2048) * 3072 + 1024 + hh * 64;
  const unsigned short* vbase = vT + (long)bh * 64 * 2048;

  bf16x8 k0 = *(const bf16x8*)(kbase + (long)tr * 3072 + tc);
  bf16x8 k1 = *(const bf16x8*)(kbase + (long)tr * 3072 + tc + 8);
  bf16x8 v0 = *(const bf16x8*)(vbase + (long)tr * 2048 + tc);
  bf16x8 v1 = *(const bf16x8*)(vbase + (long)tr * 2048 + tc + 8);

  for (int t0 = 0; t0 < 2048; t0 += 64) {
    __syncthreads();
    *(bf16x8*)&lsK[tr][tc]     = k0;
    *(bf16x8*)&lsK[tr][tc + 8] = k1;
    *(bf16x8*)&lsV[tr][tc]     = v0;
    *(bf16x8*)&lsV[tr][tc + 8] = v1;
    __syncthreads();
    if (t0 + 64 < 2048) {
      k0 = *(const bf16x8*)(kbase + (long)(t0 + 64 + tr) * 3072 + tc);
      k1 = *(const bf16x8*)(kbase + (long)(t0 + 64 + tr) * 3072 + tc + 8);
      v0 = *(const bf16x8*)(vbase + (long)tr * 2048 + t0 + 64 + tc);
      v1 = *(const bf16x8*)(vbase + (long)tr * 2048 + t0 + 64 + tc + 8);
    }

#pragma unroll
    for (int tg = 0; tg < 2; tg++) {
      bf16x8 kb[4];
#pragma unroll
      for (int kc = 0; kc < 4; kc++)
        kb[kc] = *(const bf16x8*)&lsK[tg * 32 + l32][kc * 16 + h32 * 8];

      f32x16 p0;
#pragma unroll
      for (int e = 0; e < 16; e++) p0[e] = 0.f;
      __builtin_amdgcn_s_setprio(1);
#pragma unroll
      for (int kc = 0; kc < 4; kc++)
        p0 = mfma32(kb[kc], qb0[kc], p0);
      __builtin_amdgcn_s_setprio(0);

      bf16x8 fA0, fA1;
      QG_BLOCK(p0, lip0, fA0, fA1)

      bf16x8 v00 = *(const bf16x8*)&lsV[l32][tg * 32 + h32 * 8];
      bf16x8 v01 = *(const bf16x8*)&lsV[l32][tg * 32 + 16 + h32 * 8];
      bf16x8 v10 = *(const bf16x8*)&lsV[32 + l32][tg * 32 + h32 * 8];
      bf16x8 v11 = *(const bf16x8*)&lsV[32 + l32][tg * 32 + 16 + h32 * 8];

      __builtin_amdgcn_s_setprio(1);
      oacc00 = mfma32(fA0, v00, oacc00);
      oacc00 = mfma32(fA1, v01, oacc00);
      oacc01 = mfma32(fA0, v10, oacc01);
      oacc01 = mfma32(fA1, v11, oacc01);
      __builtin_amdgcn_s_setprio(0);
    }
  }

  const float li0 = lip0 + __shfl_xor(lip0, 32);
  const float inv0 = 1.f / li0;
  const long qrow0 = (long)(b * 2048 + s0 + w * 32);
  const int dcol = hh * 64 + l32;
#pragma unroll
  for (int reg = 0; reg < 16; reg++) {
    const int rq = (reg & 3) + 8 * (reg >> 2) + 4 * h32;
    const float iv = __shfl(inv0, rq);
    const long q = qrow0 + rq;
    ctx[q * 1024 + dcol]      = f2bf(oacc00[reg] * iv);
    ctx[q * 1024 + dcol + 32] = f2bf(oacc01[reg] * iv);
  }
}

// ---------------- ln1: x1 = LN(x + ao) (bf16 out) + qo features ----------------
__global__ __launch_bounds__(256) void ln1_kernel(const float* __restrict__ x,
                                                  const unsigned short* __restrict__ ao,
                                                  const float* __restrict__ g,
                                                  const float* __restrict__ bb,
                                                  unsigned short* __restrict__ x1,
                                                  unsigned short* __restrict__ qo,
                                                  const float* __restrict__ theta) {
  const int row = blockIdx.x;
  const int tid = threadIdx.x;
  const long base = (long)row * 1024 + tid * 4;
  float4 a = *(const float4*)(x + base);
  u16x4 o = *(const u16x4*)(ao + base);
  float4 r;
  r.x = a.x + bf2f(o[0]); r.y = a.y + bf2f(o[1]);
  r.z = a.z + bf2f(o[2]); r.w = a.w + bf2f(o[3]);
  float s  = r.x + r.y + r.z + r.w;
  float ss = r.x * r.x + r.y * r.y + r.z * r.z + r.w * r.w;
  for (int off = 32; off; off >>= 1) {
    s  += __shfl_down(s, off);
    ss += __shfl_down(ss, off);
  }
  __shared__ float red[4][2];
  const int wv = tid >> 6;
  if ((tid & 63) == 0) { red[wv][0] = s; red[wv][1] = ss; }
  __syncthreads();
  s  = red[0][0] + red[1][0] + red[2][0] + red[3][0];
  ss = red[0][1] + red[1][1] + red[2][1] + red[3][1];
  const float mu  = s * (1.f / 1024.f);
  const float var = ss * (1.f / 1024.f) - mu * mu;
  const float rsv = rsqrtf(var + 1e-5f);
  float4 gv  = *(const float4*)(g + tid * 4);
  float4 bbv = *(const float4*)(bb + tid * 4);
  float y0 = (r.x - mu) * rsv * gv.x + bbv.x;
  float y1 = (r.y - mu) * rsv * gv.y + bbv.y;
  float y2 = (r.z - mu) * rsv * gv.z + bbv.z;
  float y3 = (r.w - mu) * rsv * gv.w + bbv.w;
  *(u16x4*)(x1 + base) = (u16x4){f2bf(y0), f2bf(y1), f2bf(y2), f2bf(y3)};
  if (tid < 2) {
    float yv[4] = {y0, y1, y2, y3};
    u16x4 q;
#pragma unroll
    for (int c = 0; c < 4; c++)
      q[c] = f2bf(__cosf(2.f * yv[c] + theta[tid * 4 + c]));
    *(u16x4*)(qo + (long)row * 8 + tid * 4) = q;
  }
}

// ---------------- ln2: out = LN(x1 + p0 + p1) (f32 out, bf16 ins) ----------------
__global__ __launch_bounds__(256) void ln2_kernel(const unsigned short* __restrict__ x1,
                                                  const unsigned short* __restrict__ p0,
                                                  const unsigned short* __restrict__ p1,
                                                  const float* __restrict__ g,
                                                  const float* __restrict__ bb,
                                                  float* __restrict__ out) {
  const int row = blockIdx.x;
  const int tid = threadIdx.x;
  const long base = (long)row * 1024 + tid * 4;
  u16x4 a = *(const u16x4*)(x1 + base);
  u16x4 b = *(const u16x4*)(p0 + base);
  u16x4 c = *(const u16x4*)(p1 + base);
  float4 r;
  r.x = bf2f(a[0]) + bf2f(b[0]) + bf2f(c[0]);
  r.y = bf2f(a[1]) + bf2f(b[1]) + bf2f(c[1]);
  r.z = bf2f(a[2]) + bf2f(b[2]) + bf2f(c[2]);
  r.w = bf2f(a[3]) + bf2f(b[3]) + bf2f(c[3]);
  float s  = r.x + r.y + r.z + r.w;
  float ss = r.x * r.x + r.y * r.y + r.z * r.z + r.w * r.w;
  for (int off = 32; off; off >>= 1) {
    s  += __shfl_down(s, off);
    ss += __shfl_down(ss, off);
  }
  __shared__ float red[4][2];
  const int wv = tid >> 6;
  if ((tid & 63) == 0) { red[wv][0] = s; red[wv][1] = ss; }
  __syncthreads();
  s  = red[0][0] + red[1][0] + red[2][0] + red[3][0];
  ss = red[0][1] + red[1][1] + red[2][1] + red[3][1];
  const float mu  = s * (1.f / 1024.f);
  const float var = ss * (1.f / 1024.f) - mu * mu;
  const float rsv = rsqrtf(var + 1e-5f);
  float4 gv  = *(const float4*)(g + tid * 4);
  float4 bbv = *(const float4*)(bb + tid * 4);
  float4 y;
  y.x = (r.x - mu) * rsv * gv.x + bbv.x;
  y.y = (r.y - mu) * rsv * gv.y + bbv.y;
  y.z = (r.z - mu) * rsv * gv.z + bbv.z;
  y.w = (r.w - mu) * rsv * gv.w + bbv.w;
  *(float4*)(out + base) = y;
}

extern "C" void kernel_launch(void* const* d_in, const int* in_sizes, int n_in,
                              void* d_out, int out_size, void* d_ws, size_t ws_size,
                              hipStream_t stream) {
  const float* x     = (const float*)d_in[0];
  const float* wq    = (const float*)d_in[1];
  const float* wk    = (const float*)d_in[2];
  const float* wv    = (const float*)d_in[3];
  const float* wo    = (const float*)d_in[4];
  const float* theta = (const float*)d_in[5];
  const float* w1    = (const float*)d_in[6];
  const float* w2    = (const float*)d_in[7];
  const float* g1    = (const float*)d_in[8];
  const float* b1    = (const float*)d_in[9];
  const float* g2    = (const float*)d_in[10];
  const float* b2    = (const float*)d_in[11];
  float* out = (float*)d_out;
  char* ws = (char*)d_ws;

  const long MB = 1 << 20;
  unsigned short* xb    = (unsigned short*)(ws);             // 16 MB; reused as ctx
  unsigned short* wqkvT = (unsigned short*)(ws + 16 * MB);   // 6 MB
  unsigned short* woT   = (unsigned short*)(ws + 22 * MB);   // 2 MB
  unsigned short* w2T   = (unsigned short*)(ws + 24 * MB);   // 8 MB
  unsigned short* x1b   = (unsigned short*)(ws + 32 * MB);   // 16 MB bf16
  unsigned short* aob   = (unsigned short*)(ws + 64 * MB);   // 16 MB (attn_out bf16)
  unsigned short* p0b   = aob;                               // p0 overlays attn_out
  unsigned short* p1b   = (unsigned short*)(ws + 80 * MB);   // 16 MB
  unsigned short* qkv   = (unsigned short*)(ws + 96 * MB);   // 48 MB
  unsigned short* vTb   = (unsigned short*)(ws + 144 * MB);  // 16 MB
  unsigned short* qob   = (unsigned short*)(ws + 160 * MB);  // 128 KB bf16
  unsigned short* w1tb  = (unsigned short*)(ws + 160 * MB + 128 * 1024);  // 64 KB
  unsigned short* ctx   = xb;

  // prep: x cast + all weight transposes (one launch)
  cast_x_kernel<<<8192, 256, 0, stream>>>(x, xb, 8192 * 1024 / 4);
  dim3 tb(32, 8);
  prep_weights<<<dim3(32, 128, 5), tb, 0, stream>>>(wq, wk, wv, wo, w2, w1,
                                                    wqkvT, woT, w2T, w1tb);

  // qkv = x @ [wq|wk|wv]  (M=8192, N=3072, K=1024) -> bf16
  gemm_bt3<1><<<dim3(24, 64), 256, 0, stream>>>(xb, wqkvT, qkv, 8192, 3072, 1024);

  // vT[bh][d][t] = V transpose
  vt_kernel<<<dim3(64, 2, 64), tb, 0, stream>>>(qkv, vTb);

  // flash attention -> ctx bf16 [8192][1024]  (split-Q: 128 rows/block)
  attn_kernel<<<1024, 256, 0, stream>>>(qkv, vTb, ctx);

  // attn_out = ctx @ wo -> bf16
  gemm_bt3<1><<<dim3(8, 64), 256, 0, stream>>>(ctx, woT, aob, 8192, 1024, 1024);

  // x1 = LN(x + attn_out) -> bf16; qob = bf16 cos(2*x1[:, :8] + theta)
  ln1_kernel<<<8192, 256, 0, stream>>>(x, aob, g1, b1, x1b, qob, theta);

  // ffn partials = relu(qob @ w1) @ w2 (split-K=2, BN=256) -> bf16
  ffn_fused<<<dim3(4, 32, 2), 512, 0, stream>>>(qob, w1tb, w2T, p0b, p1b, 1024, 4096);

  // out = LN(x1 + p0 + p1) -> f32
  ln2_kernel<<<8192, 256, 0, stream>>>(x1b, p0b, p1b, g2, b2, out);
}

// Round 20
// 286.762 us; speedup vs baseline: 1.0625x; 1.0625x over previous
//
#include <hip/hip_runtime.h>
#include <hip/hip_bf16.h>

// TransformerBlockQuantum on MI355X — bf16 MFMA pipeline, fp32 accumulate.
// B=4 S=2048 E=1024 F=4096 Q=8.
// R20: attn = R18 grid/tile (512 blocks, QBLK=256, same staging traffic) but
//     512 threads / 8 waves per block, each wave owning 32 q-rows (R19 shape).
//     2x waves/CU for latency hiding WITHOUT R19's doubled K/V staging.
//     Everything else identical to R18 (best = 293.5us).

typedef __attribute__((ext_vector_type(8))) short bf16x8;
typedef __attribute__((ext_vector_type(16))) float f32x16;
typedef __attribute__((ext_vector_type(4))) unsigned short u16x4;

__device__ __forceinline__ unsigned short f2bf(float f) {
  union { float f; unsigned int u; } v; v.f = f;
  return (unsigned short)((v.u + 0x7FFFu + ((v.u >> 16) & 1u)) >> 16);
}
__device__ __forceinline__ float bf2f(unsigned short h) {
  union { unsigned int u; float f; } v; v.u = ((unsigned int)h) << 16;
  return v.f;
}
__device__ __forceinline__ f32x16 mfma32(bf16x8 a, bf16x8 b, f32x16 c) {
  return __builtin_amdgcn_mfma_f32_32x32x16_bf16(a, b, c, 0, 0, 0);
}
// async global->LDS, 16B per lane. LDS dest = wave-uniform base (HW adds lane*16).
__device__ __forceinline__ void lds_cp16(const void* g, void* l) {
  __builtin_amdgcn_global_load_lds(
      (const __attribute__((address_space(1))) unsigned int*)g,
      (__attribute__((address_space(3))) unsigned int*)l, 16, 0, 0);
}

// C32-layout f32x16 (rows = r-dim over regs, cols = lane) -> two bf16 A32-frags
// (lane = col, elems = r-chunk h32*8+j and 16+h32*8+j). Pure VALU.
#define QG_CONV(P, FC0, FC1)                                                  \
  {                                                                           \
    int x0a, x0b, x1a, x1b, x2a, x2b, x3a, x3b;                               \
    asm("v_cvt_pk_bf16_f32 %0, %1, %2" : "=v"(x0a) : "v"(P[0]),  "v"(P[1]));  \
    asm("v_cvt_pk_bf16_f32 %0, %1, %2" : "=v"(x0b) : "v"(P[2]),  "v"(P[3]));  \
    asm("v_cvt_pk_bf16_f32 %0, %1, %2" : "=v"(x1a) : "v"(P[4]),  "v"(P[5]));  \
    asm("v_cvt_pk_bf16_f32 %0, %1, %2" : "=v"(x1b) : "v"(P[6]),  "v"(P[7]));  \
    asm("v_cvt_pk_bf16_f32 %0, %1, %2" : "=v"(x2a) : "v"(P[8]),  "v"(P[9]));  \
    asm("v_cvt_pk_bf16_f32 %0, %1, %2" : "=v"(x2b) : "v"(P[10]), "v"(P[11])); \
    asm("v_cvt_pk_bf16_f32 %0, %1, %2" : "=v"(x3a) : "v"(P[12]), "v"(P[13])); \
    asm("v_cvt_pk_bf16_f32 %0, %1, %2" : "=v"(x3b) : "v"(P[14]), "v"(P[15])); \
    asm("v_permlane32_swap_b32 %0, %1" : "+v"(x0a), "+v"(x1a));               \
    asm("v_permlane32_swap_b32 %0, %1" : "+v"(x0b), "+v"(x1b));               \
    asm("v_permlane32_swap_b32 %0, %1" : "+v"(x2a), "+v"(x3a));               \
    asm("v_permlane32_swap_b32 %0, %1" : "+v"(x2b), "+v"(x3b));               \
    union { int u[4]; bf16x8 v; } f0_, f1_;                                   \
    f0_.u[0] = x0a; f0_.u[1] = x0b; f0_.u[2] = x1a; f0_.u[3] = x1b;           \
    f1_.u[0] = x2a; f1_.u[1] = x2b; f1_.u[2] = x3a; f1_.u[3] = x3b;           \
    FC0 = f0_.v; FC1 = f1_.v;                                                 \
  }

// ---------------- cast x (f32 -> bf16), 4 elems/thread ----------------
__global__ __launch_bounds__(256) void cast_x_kernel(const float* __restrict__ in,
                                                     unsigned short* __restrict__ out,
                                                     int n4) {
  int i = blockIdx.x * 256 + threadIdx.x;
  if (i >= n4) return;
  float4 v = ((const float4*)in)[i];
  u16x4 o = { f2bf(v.x), f2bf(v.y), f2bf(v.z), f2bf(v.w) };
  ((u16x4*)out)[i] = o;
}

// ------------- fused weight prep: all transposes + w1t in ONE launch -------------
__global__ __launch_bounds__(256) void prep_weights(const float* __restrict__ wq,
                                                    const float* __restrict__ wk,
                                                    const float* __restrict__ wv,
                                                    const float* __restrict__ wo,
                                                    const float* __restrict__ w2,
                                                    const float* __restrict__ w1,
                                                    unsigned short* __restrict__ wqkvT,
                                                    unsigned short* __restrict__ woT,
                                                    unsigned short* __restrict__ w2T,
                                                    unsigned short* __restrict__ w1t) {
  __shared__ float tile[32][33];
  const int tx = threadIdx.x, ty = threadIdx.y;
  const int z = blockIdx.z;

  if (z == 0 && blockIdx.y >= 32) {
    if (blockIdx.y < 48) {
      const int f = (blockIdx.y - 32) * 256 + ty * 32 + tx;  // 0..4095
      unsigned short v[8];
#pragma unroll
      for (int q = 0; q < 8; q++) v[q] = f2bf(w1[q * 4096 + f]);
      *(u16x4*)(w1t + f * 8)     = (u16x4){v[0], v[1], v[2], v[3]};
      *(u16x4*)(w1t + f * 8 + 4) = (u16x4){v[4], v[5], v[6], v[7]};
    }
    return;
  }
  if (z < 4 && blockIdx.y >= 32) return;

  const float* src;
  unsigned short* dst;
  int K;
  if (z == 4)      { src = w2; dst = w2T; K = 4096; }
  else if (z == 0) { src = wq; dst = wqkvT; K = 1024; }
  else if (z == 1) { src = wk; dst = wqkvT + 1024 * 1024; K = 1024; }
  else if (z == 2) { src = wv; dst = wqkvT + 2048 * 1024; K = 1024; }
  else             { src = wo; dst = woT; K = 1024; }
  const int N = 1024;
  const int n0 = blockIdx.x * 32, k0 = blockIdx.y * 32;
#pragma unroll
  for (int i = 0; i < 32; i += 8)
    tile[ty + i][tx] = src[(long)(k0 + ty + i) * N + n0 + tx];
  __syncthreads();
#pragma unroll
  for (int i = 0; i < 32; i += 8)
    dst[(long)(n0 + ty + i) * K + k0 + tx] = f2bf(tile[tx][ty + i]);
}

// ------------- vT[bh][d=64][t=2048] = V[b,t,h,d] from qkv -------------
__global__ __launch_bounds__(256) void vt_kernel(const unsigned short* __restrict__ qkv,
                                                 unsigned short* __restrict__ vT) {
  __shared__ unsigned short tile[32][34];
  const int t0 = blockIdx.x * 32, d0 = blockIdx.y * 32, bh = blockIdx.z;
  const int b = bh >> 4, h = bh & 15;
  const int tx = threadIdx.x, ty = threadIdx.y;  // block (32,8)
  const unsigned short* src = qkv + (long)(b * 2048 + t0) * 3072 + 2048 + h * 64 + d0;
#pragma unroll
  for (int i = 0; i < 32; i += 8)
    tile[ty + i][tx] = src[(long)(ty + i) * 3072 + tx];
  __syncthreads();
  unsigned short* dst = vT + ((long)bh * 64 + d0) * 2048 + t0;
#pragma unroll
  for (int i = 0; i < 32; i += 8)
    dst[(long)(ty + i) * 2048 + tx] = tile[tx][ty + i];
}

// ---------------- GEMM: C[M,N] = A[M,K](bf16) @ BT[N,K](bf16)^T ----------------
// 128x128 tile, BK=64, 256 threads (4 waves 2Mx2N; per-wave 64x64, mfma32).
// 2 LDS buffers (64KB), counted vmcnt(8), XOR-swizzled LDS. (unchanged)
template<int EPI>  // 0: f32 out, 1: bf16 out
__global__ __launch_bounds__(256) void gemm_bt3(const unsigned short* __restrict__ A,
                                                const unsigned short* __restrict__ BT,
                                                void* __restrict__ Cv,
                                                int M, int N, int K) {
  __shared__ __align__(16) unsigned char smem[2][32768];  // per buf: A 16KB | B 16KB
  const int tid = threadIdx.x;
  const int l = tid & 63, w = tid >> 6;
  const int l32 = l & 31, h32 = l >> 5;
  const int wrm = (w >> 1) * 64;
  const int wrn = (w & 1) * 64;

  const int nx = gridDim.x;
  const int nwg = nx * gridDim.y;
  const int orig = blockIdx.y * nx + blockIdx.x;
  const int chunk = nwg >> 3;
  const int logical = (orig & 7) * chunk + (orig >> 3);
  const long m0 = (long)(logical / nx) * 128;
  const long n0 = (long)(logical % nx) * 128;

  const unsigned short* gp[8];
  unsigned ldsoff[8];
#pragma unroll
  for (int i = 0; i < 8; i++) {
    const int c = (i & 3) * 256 + tid;
    const int r = c >> 3, k8 = c & 7;
    if (i < 4) {
      gp[i] = A + (m0 + r) * (long)K + (k8 ^ (r & 7)) * 8;
      ldsoff[i] = (unsigned)c * 16;
    } else {
      gp[i] = BT + (n0 + r) * (long)K + (k8 ^ (r & 7)) * 8;
      ldsoff[i] = 16384u + (unsigned)c * 16;
    }
  }

  f32x16 acc[2][2];
#pragma unroll
  for (int mf = 0; mf < 2; mf++)
#pragma unroll
    for (int nf = 0; nf < 2; nf++)
#pragma unroll
      for (int e = 0; e < 16; e++) acc[mf][nf][e] = 0.f;

  const int NT = K >> 6;
#define STAGE(bf, t)                                                    \
  do {                                                                  \
    unsigned char* _d = &smem[bf][0];                                   \
    const long _ko = (long)(t) * 64;                                    \
    _Pragma("unroll")                                                   \
    for (int _i = 0; _i < 8; _i++)                                      \
      lds_cp16(gp[_i] + _ko, _d + ldsoff[_i]);                          \
  } while (0)

  STAGE(0, 0);
  int cur = 0;
  for (int t = 0; t < NT; t++) {
    if (t + 1 < NT) {
      STAGE(cur ^ 1, t + 1);
      asm volatile("s_waitcnt vmcnt(8)" ::: "memory");
    } else {
      asm volatile("s_waitcnt vmcnt(0)" ::: "memory");
    }
    __builtin_amdgcn_sched_barrier(0);
    __builtin_amdgcn_s_barrier();
    __builtin_amdgcn_sched_barrier(0);

    const unsigned char* bufA = &smem[cur][0];
    const unsigned char* bufB = &smem[cur][16384];
    bf16x8 af[2][4], bfr[2][4];
#pragma unroll
    for (int mf = 0; mf < 2; mf++) {
      const int r = wrm + mf * 32 + l32;
#pragma unroll
      for (int ks = 0; ks < 4; ks++)
        af[mf][ks] = *(const bf16x8*)(bufA + r * 128 + (((ks * 2 + h32) ^ (r & 7)) * 16));
    }
#pragma unroll
    for (int nf = 0; nf < 2; nf++) {
      const int r = wrn + nf * 32 + l32;
#pragma unroll
      for (int ks = 0; ks < 4; ks++)
        bfr[nf][ks] = *(const bf16x8*)(bufB + r * 128 + (((ks * 2 + h32) ^ (r & 7)) * 16));
    }
    __builtin_amdgcn_s_setprio(1);
#pragma unroll
    for (int ks = 0; ks < 4; ks++)
#pragma unroll
      for (int mf = 0; mf < 2; mf++)
#pragma unroll
        for (int nf = 0; nf < 2; nf++)
          acc[mf][nf] = mfma32(af[mf][ks], bfr[nf][ks], acc[mf][nf]);
    __builtin_amdgcn_s_setprio(0);
    __builtin_amdgcn_sched_barrier(0);
    __builtin_amdgcn_s_barrier();
    cur ^= 1;
  }
#undef STAGE

#pragma unroll
  for (int mf = 0; mf < 2; mf++)
#pragma unroll
    for (int nf = 0; nf < 2; nf++) {
      const long c0 = n0 + wrn + nf * 32 + l32;
#pragma unroll
      for (int reg = 0; reg < 16; reg++) {
        const long r0 = m0 + wrm + mf * 32 + (reg & 3) + 8 * (reg >> 2) + 4 * h32;
        if (EPI == 0) ((float*)Cv)[r0 * (long)N + c0] = acc[mf][nf][reg];
        else ((unsigned short*)Cv)[r0 * (long)N + c0] = f2bf(acc[mf][nf][reg]);
      }
    }
}

// ---------------- fused FFN, split-K, BN=256 (h converted once, used 2x) ----------
// (unchanged from R18)
__global__ __launch_bounds__(512) void ffn_fused(const unsigned short* __restrict__ qo,
                                                 const unsigned short* __restrict__ w1t,
                                                 const unsigned short* __restrict__ BT,
                                                 unsigned short* __restrict__ Cp0,
                                                 unsigned short* __restrict__ Cp1,
                                                 int N, int K) {
  __shared__ __align__(16) unsigned char sm[4 * 16384 + 32768 + 4096];
  unsigned char* lsW = sm + 65536;   // 32 slots x 1KB
  unsigned char* lsQ = sm + 98304;   // 256 rows x 16B
  const int tid = threadIdx.x;
  const int l = tid & 63, w = tid >> 6;
  const int l32 = l & 31, h32 = l >> 5;
  const int wrm = (w >> 1) * 64;   // 0,64,128,192
  const int wrn = (w & 1) * 64;    // 0,64

  const int nx = gridDim.x;                       // 4
  const int nwg = nx * gridDim.y;                 // 128 per kz
  const int orig = blockIdx.y * nx + blockIdx.x;
  const int chunk = nwg >> 3;
  const int logical = (orig & 7) * chunk + (orig >> 3);
  const long m0 = (long)(logical / nx) * 256;
  const long n0 = (long)(logical % nx) * 256;
  const int kz = blockIdx.z;
  const int NT = (K >> 6) >> 1;                   // 32 tiles per half
  const int tbase = kz * NT;
  unsigned short* C = kz ? Cp1 : Cp0;

  const unsigned short* gpB[2][2];
  unsigned offB[2];
#pragma unroll
  for (int i = 0; i < 2; i++) {
    const int c = i * 512 + tid;          // 0..1023: 128 rows x 8 chunks
    const int r = c >> 3, k8 = c & 7;
#pragma unroll
    for (int nt2 = 0; nt2 < 2; nt2++)
      gpB[nt2][i] = BT + (n0 + nt2 * 128 + r) * (long)K + (long)tbase * 64 + (k8 ^ (r & 7)) * 8;
    offB[i] = (unsigned)c * 16;
  }
  const unsigned short* w1base = w1t + (long)tbase * 64 * 8;

  const bf16x8 z8 = {0, 0, 0, 0, 0, 0, 0, 0};

#define STAGE_B(bf, t)                                                  \
  do {                                                                  \
    const long _ko = (long)(t) * 64;                                    \
    _Pragma("unroll")                                                   \
    for (int _n = 0; _n < 2; _n++) {                                    \
      unsigned char* _d = sm + ((bf) * 2 + _n) * 16384;                 \
      lds_cp16(gpB[_n][0] + _ko, _d + offB[0]);                         \
      lds_cp16(gpB[_n][1] + _ko, _d + offB[1]);                         \
    }                                                                   \
  } while (0)

  // prologue: ALL w1 slots (one wave each), qo strip, B tile 0 (both subtiles)
#pragma unroll
  for (int i = 0; i < 4; i++) {
    const int slot = i * 8 + w;
    lds_cp16(w1base + (long)(slot * 64 + l) * 8, lsW + ((unsigned)slot << 10));
  }
  if (w < 4) lds_cp16(qo + (m0 + w * 64 + l) * 8, lsQ + (unsigned)(w * 64) * 16);
  STAGE_B(0, 0);
  asm volatile("s_waitcnt vmcnt(0)" ::: "memory");
  __builtin_amdgcn_s_barrier();

  bf16x8 qof[2];
#pragma unroll
  for (int mf = 0; mf < 2; mf++)
    qof[mf] = (h32 == 0) ? *(const bf16x8*)(lsQ + (wrm + mf * 32 + l32) * 16) : z8;

  f32x16 zz;
#pragma unroll
  for (int e = 0; e < 16; e++) zz[e] = 0.f;
  f32x16 acc[2][2][2];   // [ntile][mf][nf]
#pragma unroll
  for (int nt2 = 0; nt2 < 2; nt2++)
#pragma unroll
    for (int mf = 0; mf < 2; mf++)
#pragma unroll
      for (int nf = 0; nf < 2; nf++) acc[nt2][mf][nf] = zz;

  int cur = 0;
  for (int t = 0; t < NT; t++) {
    if (t + 1 < NT) {
      STAGE_B(cur ^ 1, t + 1);
      asm volatile("s_waitcnt vmcnt(4)" ::: "memory");  // tile-t B resident
    } else {
      asm volatile("s_waitcnt vmcnt(0)" ::: "memory");
    }
    __builtin_amdgcn_sched_barrier(0);
    __builtin_amdgcn_s_barrier();
    __builtin_amdgcn_sched_barrier(0);

    // w1 frags (slot t); gen + relu + cvt BOTH mf h-tiles ONCE
    bf16x8 w1f[2];
#pragma unroll
    for (int tg = 0; tg < 2; tg++)
      w1f[tg] = (h32 == 0)
          ? *(const bf16x8*)(lsW + ((unsigned)t << 10) + (tg * 32 + l32) * 16) : z8;

    __builtin_amdgcn_s_setprio(1);
    f32x16 hC0 = mfma32(w1f[0], qof[0], zz);
    f32x16 hC1 = mfma32(w1f[1], qof[0], zz);
    f32x16 hD0 = mfma32(w1f[0], qof[1], zz);
    f32x16 hD1 = mfma32(w1f[1], qof[1], zz);
    __builtin_amdgcn_s_setprio(0);
#pragma unroll
    for (int e = 0; e < 16; e++) {
      hC0[e] = fmaxf(hC0[e], 0.f);
      hC1[e] = fmaxf(hC1[e], 0.f);
      hD0[e] = fmaxf(hD0[e], 0.f);
      hD1[e] = fmaxf(hD1[e], 0.f);
    }
    bf16x8 a0, a1, a2, a3, b0, b1, b2, b3;
    QG_CONV(hC0, a0, a1)
    QG_CONV(hC1, a2, a3)
    QG_CONV(hD0, b0, b1)
    QG_CONV(hD1, b2, b3)

    // apply to both N-subtiles
#pragma unroll
    for (int nt2 = 0; nt2 < 2; nt2++) {
      const unsigned char* bufB = sm + (cur * 2 + nt2) * 16384;
      bf16x8 bfr[2][4];
#pragma unroll
      for (int nf = 0; nf < 2; nf++) {
        const int r = wrn + nf * 32 + l32;
#pragma unroll
        for (int ks = 0; ks < 4; ks++)
          bfr[nf][ks] = *(const bf16x8*)(bufB + r * 128 + (((ks * 2 + h32) ^ (r & 7)) * 16));
      }
      __builtin_amdgcn_s_setprio(1);
      acc[nt2][0][0] = mfma32(a0, bfr[0][0], acc[nt2][0][0]);
      acc[nt2][0][0] = mfma32(a1, bfr[0][1], acc[nt2][0][0]);
      acc[nt2][0][0] = mfma32(a2, bfr[0][2], acc[nt2][0][0]);
      acc[nt2][0][0] = mfma32(a3, bfr[0][3], acc[nt2][0][0]);
      acc[nt2][0][1] = mfma32(a0, bfr[1][0], acc[nt2][0][1]);
      acc[nt2][0][1] = mfma32(a1, bfr[1][1], acc[nt2][0][1]);
      acc[nt2][0][1] = mfma32(a2, bfr[1][2], acc[nt2][0][1]);
      acc[nt2][0][1] = mfma32(a3, bfr[1][3], acc[nt2][0][1]);
      acc[nt2][1][0] = mfma32(b0, bfr[0][0], acc[nt2][1][0]);
      acc[nt2][1][0] = mfma32(b1, bfr[0][1], acc[nt2][1][0]);
      acc[nt2][1][0] = mfma32(b2, bfr[0][2], acc[nt2][1][0]);
      acc[nt2][1][0] = mfma32(b3, bfr[0][3], acc[nt2][1][0]);
      acc[nt2][1][1] = mfma32(b0, bfr[1][0], acc[nt2][1][1]);
      acc[nt2][1][1] = mfma32(b1, bfr[1][1], acc[nt2][1][1]);
      acc[nt2][1][1] = mfma32(b2, bfr[1][2], acc[nt2][1][1]);
      acc[nt2][1][1] = mfma32(b3, bfr[1][3], acc[nt2][1][1]);
      __builtin_amdgcn_s_setprio(0);
    }

    __builtin_amdgcn_sched_barrier(0);
    __builtin_amdgcn_s_barrier();
    cur ^= 1;
  }
#undef STAGE_B

#pragma unroll
  for (int nt2 = 0; nt2 < 2; nt2++)
#pragma unroll
    for (int mf = 0; mf < 2; mf++)
#pragma unroll
      for (int nf = 0; nf < 2; nf++) {
        const long c0 = n0 + nt2 * 128 + wrn + nf * 32 + l32;
#pragma unroll
        for (int reg = 0; reg < 16; reg++) {
          const long r0 = m0 + wrm + mf * 32 + (reg & 3) + 8 * (reg >> 2) + 4 * h32;
          C[r0 * (long)N + c0] = f2bf(acc[nt2][mf][nf][reg]);
        }
      }
}

// ---------------- flash attention: 32x32x16, swapped QK^T, 8 waves ----------------
// R20: 512 threads, QBLK=256 (wave owns 32 q-rows), grid 512. Staging split
// across 8 waves (tr=tid>>3, one 16B K + 16B V chunk per thread).
#define QG_BLOCK(P, LIP, FC0, FC1)                                            \
  {                                                                           \
    _Pragma("unroll")                                                         \
    for (int e = 0; e < 16; e++)                                              \
      asm("v_exp_f32 %0, %1" : "=v"(P[e]) : "v"(P[e]));                       \
    float s_ = 0.f;                                                           \
    _Pragma("unroll")                                                         \
    for (int e = 0; e < 16; e++) s_ += P[e];                                  \
    LIP += s_;                                                                \
    QG_CONV(P, FC0, FC1)                                                      \
  }

__global__ __launch_bounds__(512) void attn_kernel(const unsigned short* __restrict__ qkv,
                                                   const unsigned short* __restrict__ vT,
                                                   unsigned short* __restrict__ ctx) {
  __shared__ __align__(16) unsigned short lsK[64][72];      // [t][d]
  __shared__ __align__(16) unsigned short lsV[64][72];      // [d][t]

  const int tid = threadIdx.x;
  const int l = tid & 63, w = tid >> 6;                     // 8 waves
  const int l32 = l & 31, h32 = l >> 5;

  const int orig = blockIdx.x;                  // 0..511
  const int logical = (orig & 7) * 64 + (orig >> 3);
  const int s0 = (logical & 7) * 256;
  const int bh = logical >> 3;
  const int b = bh >> 4, hh = bh & 15;

  const float QSC = 0.18033688f;
  // Q B-frags: q = s0 + w*32 + l32, d = kc*16 + h32*8 .. +7 (one 32-row group)
  const unsigned short* qg_base = qkv + (long)(b * 2048 + s0 + w * 32) * 3072 + hh * 64;
  bf16x8 qb0[4];
#pragma unroll
  for (int kc = 0; kc < 4; kc++) {
    bf16x8 t0v = *(const bf16x8*)(qg_base + (long)l32 * 3072 + kc * 16 + h32 * 8);
#pragma unroll
    for (int j = 0; j < 8; j++)
      t0v[j] = (short)f2bf(bf2f((unsigned short)t0v[j]) * QSC);
    qb0[kc] = t0v;
  }

  f32x16 oacc00, oacc01;
#pragma unroll
  for (int e = 0; e < 16; e++) { oacc00[e] = 0.f; oacc01[e] = 0.f; }
  float lip0 = 0.f;

  // staging: 512 threads, each one 16B chunk of K and of V
  const int tr = tid >> 3;            // 0..63
  const int tc = (tid & 7) * 8;       // 0..56 elems
  const unsigned short* kbase = qkv + (long)(b * 2048) * 3072 + 1024 + hh * 64;
  const unsigned short* vbase = vT + (long)bh * 64 * 2048;

  bf16x8 k0 = *(const bf16x8*)(kbase + (long)tr * 3072 + tc);
  bf16x8 v0 = *(const bf16x8*)(vbase + (long)tr * 2048 + tc);

  for (int t0 = 0; t0 < 2048; t0 += 64) {
    __syncthreads();
    *(bf16x8*)&lsK[tr][tc] = k0;
    *(bf16x8*)&lsV[tr][tc] = v0;
    __syncthreads();
    if (t0 + 64 < 2048) {
      k0 = *(const bf16x8*)(kbase + (long)(t0 + 64 + tr) * 3072 + tc);
      v0 = *(const bf16x8*)(vbase + (long)tr * 2048 + t0 + 64 + tc);
    }

#pragma unroll
    for (int tg = 0; tg < 2; tg++) {
      bf16x8 kb[4];
#pragma unroll
      for (int kc = 0; kc < 4; kc++)
        kb[kc] = *(const bf16x8*)&lsK[tg * 32 + l32][kc * 16 + h32 * 8];

      f32x16 p0;
#pragma unroll
      for (int e = 0; e < 16; e++) p0[e] = 0.f;
      __builtin_amdgcn_s_setprio(1);
#pragma unroll
      for (int kc = 0; kc < 4; kc++)
        p0 = mfma32(kb[kc], qb0[kc], p0);
      __builtin_amdgcn_s_setprio(0);

      bf16x8 fA0, fA1;
      QG_BLOCK(p0, lip0, fA0, fA1)

      bf16x8 v00 = *(const bf16x8*)&lsV[l32][tg * 32 + h32 * 8];
      bf16x8 v01 = *(const bf16x8*)&lsV[l32][tg * 32 + 16 + h32 * 8];
      bf16x8 v10 = *(const bf16x8*)&lsV[32 + l32][tg * 32 + h32 * 8];
      bf16x8 v11 = *(const bf16x8*)&lsV[32 + l32][tg * 32 + 16 + h32 * 8];

      __builtin_amdgcn_s_setprio(1);
      oacc00 = mfma32(fA0, v00, oacc00);
      oacc00 = mfma32(fA1, v01, oacc00);
      oacc01 = mfma32(fA0, v10, oacc01);
      oacc01 = mfma32(fA1, v11, oacc01);
      __builtin_amdgcn_s_setprio(0);
    }
  }

  const float li0 = lip0 + __shfl_xor(lip0, 32);
  const float inv0 = 1.f / li0;
  const long qrow0 = (long)(b * 2048 + s0 + w * 32);
  const int dcol = hh * 64 + l32;
#pragma unroll
  for (int reg = 0; reg < 16; reg++) {
    const int rq = (reg & 3) + 8 * (reg >> 2) + 4 * h32;
    const float iv = __shfl(inv0, rq);
    const long q = qrow0 + rq;
    ctx[q * 1024 + dcol]      = f2bf(oacc00[reg] * iv);
    ctx[q * 1024 + dcol + 32] = f2bf(oacc01[reg] * iv);
  }
}

// ---------------- ln1: x1 = LN(x + ao) (bf16 out) + qo features ----------------
__global__ __launch_bounds__(256) void ln1_kernel(const float* __restrict__ x,
                                                  const unsigned short* __restrict__ ao,
                                                  const float* __restrict__ g,
                                                  const float* __restrict__ bb,
                                                  unsigned short* __restrict__ x1,
                                                  unsigned short* __restrict__ qo,
                                                  const float* __restrict__ theta) {
  const int row = blockIdx.x;
  const int tid = threadIdx.x;
  const long base = (long)row * 1024 + tid * 4;
  float4 a = *(const float4*)(x + base);
  u16x4 o = *(const u16x4*)(ao + base);
  float4 r;
  r.x = a.x + bf2f(o[0]); r.y = a.y + bf2f(o[1]);
  r.z = a.z + bf2f(o[2]); r.w = a.w + bf2f(o[3]);
  float s  = r.x + r.y + r.z + r.w;
  float ss = r.x * r.x + r.y * r.y + r.z * r.z + r.w * r.w;
  for (int off = 32; off; off >>= 1) {
    s  += __shfl_down(s, off);
    ss += __shfl_down(ss, off);
  }
  __shared__ float red[4][2];
  const int wv = tid >> 6;
  if ((tid & 63) == 0) { red[wv][0] = s; red[wv][1] = ss; }
  __syncthreads();
  s  = red[0][0] + red[1][0] + red[2][0] + red[3][0];
  ss = red[0][1] + red[1][1] + red[2][1] + red[3][1];
  const float mu  = s * (1.f / 1024.f);
  const float var = ss * (1.f / 1024.f) - mu * mu;
  const float rsv = rsqrtf(var + 1e-5f);
  float4 gv  = *(const float4*)(g + tid * 4);
  float4 bbv = *(const float4*)(bb + tid * 4);
  float y0 = (r.x - mu) * rsv * gv.x + bbv.x;
  float y1 = (r.y - mu) * rsv * gv.y + bbv.y;
  float y2 = (r.z - mu) * rsv * gv.z + bbv.z;
  float y3 = (r.w - mu) * rsv * gv.w + bbv.w;
  *(u16x4*)(x1 + base) = (u16x4){f2bf(y0), f2bf(y1), f2bf(y2), f2bf(y3)};
  if (tid < 2) {
    float yv[4] = {y0, y1, y2, y3};
    u16x4 q;
#pragma unroll
    for (int c = 0; c < 4; c++)
      q[c] = f2bf(__cosf(2.f * yv[c] + theta[tid * 4 + c]));
    *(u16x4*)(qo + (long)row * 8 + tid * 4) = q;
  }
}

// ---------------- ln2: out = LN(x1 + p0 + p1) (f32 out, bf16 ins) ----------------
__global__ __launch_bounds__(256) void ln2_kernel(const unsigned short* __restrict__ x1,
                                                  const unsigned short* __restrict__ p0,
                                                  const unsigned short* __restrict__ p1,
                                                  const float* __restrict__ g,
                                                  const float* __restrict__ bb,
                                                  float* __restrict__ out) {
  const int row = blockIdx.x;
  const int tid = threadIdx.x;
  const long base = (long)row * 1024 + tid * 4;
  u16x4 a = *(const u16x4*)(x1 + base);
  u16x4 b = *(const u16x4*)(p0 + base);
  u16x4 c = *(const u16x4*)(p1 + base);
  float4 r;
  r.x = bf2f(a[0]) + bf2f(b[0]) + bf2f(c[0]);
  r.y = bf2f(a[1]) + bf2f(b[1]) + bf2f(c[1]);
  r.z = bf2f(a[2]) + bf2f(b[2]) + bf2f(c[2]);
  r.w = bf2f(a[3]) + bf2f(b[3]) + bf2f(c[3]);
  float s  = r.x + r.y + r.z + r.w;
  float ss = r.x * r.x + r.y * r.y + r.z * r.z + r.w * r.w;
  for (int off = 32; off; off >>= 1) {
    s  += __shfl_down(s, off);
    ss += __shfl_down(ss, off);
  }
  __shared__ float red[4][2];
  const int wv = tid >> 6;
  if ((tid & 63) == 0) { red[wv][0] = s; red[wv][1] = ss; }
  __syncthreads();
  s  = red[0][0] + red[1][0] + red[2][0] + red[3][0];
  ss = red[0][1] + red[1][1] + red[2][1] + red[3][1];
  const float mu  = s * (1.f / 1024.f);
  const float var = ss * (1.f / 1024.f) - mu * mu;
  const float rsv = rsqrtf(var + 1e-5f);
  float4 gv  = *(const float4*)(g + tid * 4);
  float4 bbv = *(const float4*)(bb + tid * 4);
  float4 y;
  y.x = (r.x - mu) * rsv * gv.x + bbv.x;
  y.y = (r.y - mu) * rsv * gv.y + bbv.y;
  y.z = (r.z - mu) * rsv * gv.z + bbv.z;
  y.w = (r.w - mu) * rsv * gv.w + bbv.w;
  *(float4*)(out + base) = y;
}

extern "C" void kernel_launch(void* const* d_in, const int* in_sizes, int n_in,
                              void* d_out, int out_size, void* d_ws, size_t ws_size,
                              hipStream_t stream) {
  const float* x     = (const float*)d_in[0];
  const float* wq    = (const float*)d_in[1];
  const float* wk    = (const float*)d_in[2];
  const float* wv    = (const float*)d_in[3];
  const float* wo    = (const float*)d_in[4];
  const float* theta = (const float*)d_in[5];
  const float* w1    = (const float*)d_in[6];
  const float* w2    = (const float*)d_in[7];
  const float* g1    = (const float*)d_in[8];
  const float* b1    = (const float*)d_in[9];
  const float* g2    = (const float*)d_in[10];
  const float* b2    = (const float*)d_in[11];
  float* out = (float*)d_out;
  char* ws = (char*)d_ws;

  const long MB = 1 << 20;
  unsigned short* xb    = (unsigned short*)(ws);             // 16 MB; reused as ctx
  unsigned short* wqkvT = (unsigned short*)(ws + 16 * MB);   // 6 MB
  unsigned short* woT   = (unsigned short*)(ws + 22 * MB);   // 2 MB
  unsigned short* w2T   = (unsigned short*)(ws + 24 * MB);   // 8 MB
  unsigned short* x1b   = (unsigned short*)(ws + 32 * MB);   // 16 MB bf16
  unsigned short* aob   = (unsigned short*)(ws + 64 * MB);   // 16 MB (attn_out bf16)
  unsigned short* p0b   = aob;                               // p0 overlays attn_out
  unsigned short* p1b   = (unsigned short*)(ws + 80 * MB);   // 16 MB
  unsigned short* qkv   = (unsigned short*)(ws + 96 * MB);   // 48 MB
  unsigned short* vTb   = (unsigned short*)(ws + 144 * MB);  // 16 MB
  unsigned short* qob   = (unsigned short*)(ws + 160 * MB);  // 128 KB bf16
  unsigned short* w1tb  = (unsigned short*)(ws + 160 * MB + 128 * 1024);  // 64 KB
  unsigned short* ctx   = xb;

  // prep: x cast + all weight transposes (one launch)
  cast_x_kernel<<<8192, 256, 0, stream>>>(x, xb, 8192 * 1024 / 4);
  dim3 tb(32, 8);
  prep_weights<<<dim3(32, 128, 5), tb, 0, stream>>>(wq, wk, wv, wo, w2, w1,
                                                    wqkvT, woT, w2T, w1tb);

  // qkv = x @ [wq|wk|wv]  (M=8192, N=3072, K=1024) -> bf16
  gemm_bt3<1><<<dim3(24, 64), 256, 0, stream>>>(xb, wqkvT, qkv, 8192, 3072, 1024);

  // vT[bh][d][t] = V transpose
  vt_kernel<<<dim3(64, 2, 64), tb, 0, stream>>>(qkv, vTb);

  // flash attention -> ctx bf16 [8192][1024]  (8 waves, QBLK=256)
  attn_kernel<<<512, 512, 0, stream>>>(qkv, vTb, ctx);

  // attn_out = ctx @ wo -> bf16
  gemm_bt3<1><<<dim3(8, 64), 256, 0, stream>>>(ctx, woT, aob, 8192, 1024, 1024);

  // x1 = LN(x + attn_out) -> bf16; qob = bf16 cos(2*x1[:, :8] + theta)
  ln1_kernel<<<8192, 256, 0, stream>>>(x, aob, g1, b1, x1b, qob, theta);

  // ffn partials = relu(qob @ w1) @ w2 (split-K=2, BN=256) -> bf16
  ffn_fused<<<dim3(4, 32, 2), 512, 0, stream>>>(qob, w1tb, w2T, p0b, p1b, 1024, 4096);

  // out = LN(x1 + p0 + p1) -> f32
  ln2_kernel<<<8192, 256, 0, stream>>>(x1b, p0b, p1b, g2, b2, out);
}